// Round 8
// baseline (239.455 us; speedup 1.0000x reference)
//
#include <hip/hip_runtime.h>
#include <hip/hip_bf16.h>

#define NHEAD 8
#define DKH 64
#define DMODEL 512
#define SEQ 4096
#define BATCH 2
#define MROWS (BATCH * SEQ)  // 8192

using bf16x8 = __attribute__((ext_vector_type(8))) short;
using s16x4  = __attribute__((ext_vector_type(4))) short;
using f32x4  = __attribute__((ext_vector_type(4))) float;
using f32x16 = __attribute__((ext_vector_type(16))) float;

__device__ __forceinline__ float b2f(unsigned short u) {
    union { unsigned short u; __hip_bfloat16 h; } c; c.u = u; return __bfloat162float(c.h);
}
// round-half-up f32->bf16: 2 VALU ops, max rel err 2^-9.
__device__ __forceinline__ short rhu(float x) {
    union { float f; unsigned u; } c; c.f = x;
    return (short)((c.u + 0x8000u) >> 16);
}

// HW convert+pack: two f32 -> one dword of 2 bf16 (RNE). 1 VALU instr.
__device__ __forceinline__ unsigned cvtpk(float lo, float hi) {
    unsigned r;
    asm("v_cvt_pk_bf16_f32 %0, %1, %2" : "=v"(r) : "v"(lo), "v"(hi));
    return r;
}

// Bare v_exp_f32 (2^x). Fixed-max softmax keeps inputs in normal range.
#if __has_builtin(__builtin_amdgcn_exp2f)
#define EXP2F(x) __builtin_amdgcn_exp2f(x)
#else
#define EXP2F(x) exp2f(x)
#endif

// Direct global->LDS DMA, 16 B/lane. LDS dest must be WAVE-UNIFORM base
// (HW adds lane*16); global src is per-lane (m104/m173).
__device__ __forceinline__ void gload_lds16(const void* g, void* l) {
    __builtin_amdgcn_global_load_lds(
        (const __attribute__((address_space(1))) void*)g,
        (__attribute__((address_space(3))) void*)l,
        16, 0, 0);
}

// T1-bijective XCD remap for 256-tile GEMM grids (nwg=256, 8 XCDs, 32/XCD).
// fid round-robins XCDs in dispatch order; L-chunks of 32 consecutive tiles
// land on one XCD. L is channel-fastest, so each XCD covers all 4 channel
// blocks of its 8 token panels -> data panel read 1x HBM + 3x L2.
// Bijection proof: fid = 8a+b (a<32,b<8) -> L = 32b+a covers [0,256) 1:1.
__device__ __forceinline__ void xcd_remap(int fid, int& tok, int& ch) {
    const int L = (fid & 7) * 32 + (fid >> 3);
    tok = L >> 2;
    ch  = L & 3;
}

// ---------------------------------------------------------------------------
// Pre-convert pass: fp32 -> bf16 for q,k,v and all four weight matrices so
// every GEMM operand stages via global_load_lds. Memory-bound (~81 MB moved,
// ~15 us). dst segments contiguous: qb | kb | vb | Wqb | Wkb | Wvb | Wob.
// ---------------------------------------------------------------------------
#define QG ((size_t)MROWS * DMODEL / 8)   // 524288 8-elem groups per tensor
#define WG ((size_t)DMODEL * DMODEL / 8)  // 32768 per weight

__global__ __launch_bounds__(256) void convert_kernel(
    const float* __restrict__ q, const float* __restrict__ k, const float* __restrict__ v,
    const float* __restrict__ Wq, const float* __restrict__ Wk,
    const float* __restrict__ Wv, const float* __restrict__ Wo,
    short* __restrict__ dst) {
    const size_t i = (size_t)blockIdx.x * 256 + threadIdx.x;  // 8-elem group
    const float* src;
    size_t off;
    if (i < 3 * QG) {
        size_t s = i / QG;                 // pow2 shift
        off = (i - s * QG) * 8;
        src = (s == 0) ? q : (s == 1) ? k : v;
    } else {
        size_t j = i - 3 * QG;
        size_t s = j / WG;
        off = (j - s * WG) * 8;
        src = (s == 0) ? Wq : (s == 1) ? Wk : (s == 2) ? Wv : Wo;
    }
    float4 a = *(const float4*)(src + off);
    float4 b = *(const float4*)(src + off + 4);
    union { unsigned u[4]; bf16x8 v8; } t;
    t.u[0] = cvtpk(a.x, a.y);
    t.u[1] = cvtpk(a.z, a.w);
    t.u[2] = cvtpk(b.x, b.y);
    t.u[3] = cvtpk(b.z, b.w);
    *(bf16x8*)&dst[i * 8] = t.v8;
}

// ---------------------------------------------------------------------------
// GEMM core. K-loop = round-4 2-phase dbuf DMA. Round-5 wide-store epilogues:
//  EPI 1 [Q,K]: m=CHANNEL, n=token -> r spans dk -> 8-B s16x4 stores
//  EPI 2 [V^T]: m=TOKEN, n=channel -> r spans 4 consecutive kappa slots
//  EPI 0 [O]:   m=OUT-CHANNEL, n=token -> r spans 4 fp32 cols -> 16-B stores
// ---------------------------------------------------------------------------
template <int EPI, int TM>
__device__ __forceinline__ void gemm_core(const short* __restrict__ A,
                                          const short* __restrict__ W,
                                          const float* __restrict__ bias,
                                          void* __restrict__ out,
                                          int bm, int bn) {
    constexpr int MT = TM / 32;            // 16-row tiles per wave (m dir)
    constexpr int AI = TM / 32;            // lA DMA instrs per wave
    __shared__ __align__(128) short lA[2][TM * 64];
    __shared__ __align__(128) short lB[2][128 * 64];

    const int tid  = threadIdx.x;
    const int lane = tid & 63;
    const int w    = tid >> 6;
    const int wr = w >> 1, wc = w & 1;
    const int g = lane >> 4, ln = lane & 15;
    const int l8 = lane >> 3, cb = lane & 7;   // DMA: row-in-group, col-group
    const int sw8 = cb ^ l8;                   // pre-swizzled global k8-group

    const f32x4 zero = {0.f, 0.f, 0.f, 0.f};
    f32x4 acc[MT][4];
    for (int mt = 0; mt < MT; mt++)
        for (int nt = 0; nt < 4; nt++) acc[mt][nt] = zero;

    auto stage = [&](int buf, int kb) {
        for (int i = 0; i < AI; i++) {
            const int rb = w * (8 * AI) + i * 8;     // wave-uniform row base
            gload_lds16(&A[(size_t)(bm + rb + l8) * DMODEL + kb + sw8 * 8],
                        &lA[buf][rb * 64]);
        }
        for (int i = 0; i < 4; i++) {
            const int rb = w * 32 + i * 8;
            gload_lds16(&W[(size_t)(bn + rb + l8) * DMODEL + kb + sw8 * 8],
                        &lB[buf][rb * 64]);
        }
    };

    stage(0, 0);
    int cur = 0;
    for (int kb = 0; kb < DMODEL; kb += 64) {
        __syncthreads();   // vmcnt(0) drain: prefetch had full compute phase
        if (kb + 64 < DMODEL) stage(cur ^ 1, kb + 64);   // prefetch next tile

        for (int ks = 0; ks < 2; ks++) {
            const int xr = (ks * 4 + g) ^ (ln & 7);  // swizzled 16B slot
            bf16x8 af[MT], bf[4];
            for (int mt = 0; mt < MT; mt++) {
                const int row = wr * 16 * MT + mt * 16 + ln;
                af[mt] = *(const bf16x8*)&lA[cur][row * 64 + xr * 8];
            }
            for (int nt = 0; nt < 4; nt++) {
                const int row = wc * 64 + nt * 16 + ln;
                bf[nt] = *(const bf16x8*)&lB[cur][row * 64 + xr * 8];
            }
            for (int mt = 0; mt < MT; mt++)
                for (int nt = 0; nt < 4; nt++)
                    acc[mt][nt] = __builtin_amdgcn_mfma_f32_16x16x32_bf16(
                        af[mt], bf[nt], acc[mt][nt], 0, 0, 0);
        }
        cur ^= 1;
    }

    if (EPI == 1) {
        // m = channel (2 heads per 128-tile), n = token. 8-B stores.
        for (int mt = 0; mt < MT; mt++) {
            const int ch = bm + wr * 16 * MT + mt * 16 + g * 4;   // quad base
            const int hh = ch >> 6, dk = ch & 63;
            const float4 bz = *(const float4*)&bias[ch];
            for (int nt = 0; nt < 4; nt++) {
                const int n = bn + wc * 64 + nt * 16 + ln;        // token
                const int bb = n >> 12, s = n & 4095;
                union { unsigned u[2]; s16x4 v; } pk;
                pk.u[0] = cvtpk(acc[mt][nt][0] + bz.x, acc[mt][nt][1] + bz.y);
                pk.u[1] = cvtpk(acc[mt][nt][2] + bz.z, acc[mt][nt][3] + bz.w);
                *(s16x4*)&((short*)out)[(((size_t)(bb * NHEAD + hh)) * SEQ + s) * DKH + dk] = pk.v;
            }
        }
    } else if (EPI == 2) {
        // m = token, n = channel. Quad-aligned tokens -> 4 consecutive kappa.
        for (int mt = 0; mt < MT; mt++) {
            const int m = bm + wr * 16 * MT + mt * 16 + g * 4;    // token quad
            const int bb = m >> 12, s = m & 4095;
            const int sl = s & 127, sh = s & ~127;
            const int kt = sl >> 5, kk = sl & 31;                 // lo = 0
            const int t = kk >> 3, hb = (kk >> 2) & 1;
            const int kap = kt * 32 + (t >> 1) * 16 + hb * 8 + (t & 1) * 4;
            for (int nt = 0; nt < 4; nt++) {
                const int chn = bn + wc * 64 + nt * 16 + ln;      // channel
                const int hh = chn >> 6, dk = chn & 63;
                const float bz = bias[chn];
                union { unsigned u[2]; s16x4 v; } pk;
                pk.u[0] = cvtpk(acc[mt][nt][0] + bz, acc[mt][nt][1] + bz);
                pk.u[1] = cvtpk(acc[mt][nt][2] + bz, acc[mt][nt][3] + bz);
                *(s16x4*)&((short*)out)[(((size_t)(bb * NHEAD + hh)) * DKH + dk) * SEQ + sh + kap] = pk.v;
            }
        }
    } else {
        // EPI 0: m = out-channel, n = token. 16-B float4 stores.
        for (int mt = 0; mt < MT; mt++) {
            const int ch = bm + wr * 16 * MT + mt * 16 + g * 4;
            const float4 bz = *(const float4*)&bias[ch];
            for (int nt = 0; nt < 4; nt++) {
                const int n = bn + wc * 64 + nt * 16 + ln;        // token
                float4 o;
                o.x = acc[mt][nt][0] + bz.x;
                o.y = acc[mt][nt][1] + bz.y;
                o.z = acc[mt][nt][2] + bz.z;
                o.w = acc[mt][nt][3] + bz.w;
                *(float4*)&((float*)out)[(size_t)n * DMODEL + ch] = o;
            }
        }
    }
}

// Merged Q/K/V projections with XCD/L2 tile remap.
// z=0 Q, z=1 K: A = weights (channels on M), B = data (tokens on N).
// z=2 V: A = data (tokens on M), B = weights (channels on N).
__global__ __launch_bounds__(256) void qkv_kernel(
    const short* __restrict__ qb, const short* __restrict__ kb, const short* __restrict__ vb,
    const short* __restrict__ Wqb, const short* __restrict__ Wkb, const short* __restrict__ Wvb,
    const float* __restrict__ bq, const float* __restrict__ bk, const float* __restrict__ bv,
    short* __restrict__ Qh, short* __restrict__ Kh, short* __restrict__ Vt) {
    int tok, ch;
    xcd_remap(blockIdx.x + 64 * blockIdx.y, tok, ch);
    if (blockIdx.z == 0) {
        gemm_core<1, 128>(Wqb, qb, bq, Qh, ch * 128, tok * 128);
    } else if (blockIdx.z == 1) {
        gemm_core<1, 128>(Wkb, kb, bk, Kh, ch * 128, tok * 128);
    } else {
        gemm_core<2, 128>(vb, Wvb, bv, Vt, tok * 128, ch * 128);
    }
}

// oproj: A = Wo (out-channels on M), B = concat (tokens on N). 128x128 tiles,
// grid 256 blocks = one full round; same XCD/L2 remap.
__global__ __launch_bounds__(256) void oproj_kernel(
    const short* __restrict__ Wob, const short* __restrict__ concat,
    const float* __restrict__ bias, float* __restrict__ out) {
    int tok, ch;
    xcd_remap(blockIdx.x + 64 * blockIdx.y, tok, ch);
    gemm_core<0, 128>(Wob, concat, bias, out, ch * 128, tok * 128);
}

// ---------------------------------------------------------------------------
// Flash attention — ROUND-5 BODY RESTORED (the verified-passing structure:
// stage -> sync -> compute -> sync). Round 6's register-staged T14 pipeline
// FAILED correctness (absmax 392) by a mechanism not identified from source;
// it is quarantined until understood. This round adds only T5 setprio
// (scheduler hint, correctness-inert) around the two MFMA clusters.
// History: r0 cvtpk+exp2 diet: 140.9 -> 93.3 us, MfmaUtil 21 -> 33%.
// ---------------------------------------------------------------------------
__global__ __launch_bounds__(256, 4) void attn_kernel(
    const short* __restrict__ Qh, const short* __restrict__ Kh,
    const short* __restrict__ Vt, short* __restrict__ concat) {
    const int tid  = threadIdx.x;
    const int lane = tid & 63;
    const int w    = tid >> 6;
    const int c  = lane & 31;
    const int h5 = lane >> 5;
    const int qsel = w & 1;
    const int ksel = w >> 1;
    const int bh = blockIdx.y;
    const int b = bh >> 3, h = bh & 7;
    const int qq = blockIdx.x * 64 + qsel * 32 + c;

    const short* Qp = Qh + (size_t)bh * SEQ * DKH;
    const short* Kp = Kh + (size_t)bh * SEQ * DKH;
    const short* Vp = Vt + (size_t)bh * DKH * SEQ;   // [dk][perm(s)]

    __shared__ __align__(16) char smem[35840];
    short* lK = (short*)smem;              // [128][72]
    short* lV = (short*)(smem + 18432);    // [64][136]
    float* cO = (float*)smem;              // combine area (aliased)
    float* cL = (float*)(smem + 32768);

    const float QS = 0.125f * 1.44269504f;
    bf16x8 qf[4];
    for (int ks = 0; ks < 4; ks++) {
        bf16x8 raw = *(const bf16x8*)&Qp[(size_t)qq * DKH + ks * 16 + h5 * 8];
        union { unsigned u[4]; bf16x8 v; } t;
        for (int j = 0; j < 4; j++)
            t.u[j] = cvtpk(b2f((unsigned short)raw[2 * j]) * QS,
                           b2f((unsigned short)raw[2 * j + 1]) * QS);
        qf[ks] = t.v;
    }

    float l_self = 0.f;
    f32x16 o_acc[2];
    for (int dt = 0; dt < 2; dt++)
        for (int r = 0; r < 16; r++) o_acc[dt][r] = 0.f;

    for (int kb = 0; kb < SEQ; kb += 128) {
        for (int i = 0; i < 4; i++) {
            int vv = tid + i * 256;
            {
                int row = vv >> 3, cv = vv & 7;
                *(bf16x8*)&lK[row * 72 + cv * 8] =
                    *(const bf16x8*)&Kp[(size_t)(kb + row) * DKH + cv * 8];
            }
            {
                int dk = vv >> 4, kc = vv & 15;
                *(bf16x8*)&lV[dk * 136 + kc * 8] =
                    *(const bf16x8*)&Vp[(size_t)dk * SEQ + kb + kc * 8];
            }
        }
        __syncthreads();

        f32x16 st[2];
        for (int kt = 0; kt < 2; kt++)
            for (int r = 0; r < 16; r++) st[kt][r] = -12.f;
        __builtin_amdgcn_s_setprio(1);
        for (int ks = 0; ks < 4; ks++)
            for (int kt = 0; kt < 2; kt++) {
                bf16x8 kf = *(const bf16x8*)&lK[(ksel * 64 + kt * 32 + c) * 72 + ks * 16 + h5 * 8];
                st[kt] = __builtin_amdgcn_mfma_f32_32x32x16_bf16(kf, qf[ks], st[kt], 0, 0, 0);
            }
        __builtin_amdgcn_s_setprio(0);

        for (int kt = 0; kt < 2; kt++)
            for (int r = 0; r < 16; r++) {
                float p = EXP2F(st[kt][r]);
                st[kt][r] = p;
                l_self += p;
            }

        __builtin_amdgcn_s_setprio(1);
        for (int ks2 = 0; ks2 < 4; ks2++) {
            const int kt = ks2 >> 1, ob = 8 * (ks2 & 1);
            union { unsigned u[4]; bf16x8 v; } pf;
            for (int j = 0; j < 4; j++)
                pf.u[j] = cvtpk(st[kt][ob + 2 * j], st[kt][ob + 2 * j + 1]);
            const int colg = (ksel * 4 + ks2) * 16 + h5 * 8;
            for (int dt = 0; dt < 2; dt++) {
                bf16x8 vf = *(const bf16x8*)&lV[(dt * 32 + c) * 136 + colg];
                o_acc[dt] = __builtin_amdgcn_mfma_f32_32x32x16_bf16(vf, pf.v, o_acc[dt], 0, 0, 0);
            }
        }
        __builtin_amdgcn_s_setprio(0);
        __syncthreads();
    }

    const float half_l = l_self + __shfl_xor(l_self, 32);
    if (ksel == 1) {
        for (int dt = 0; dt < 2; dt++)
            for (int r = 0; r < 16; r++)
                cO[(((qsel * 2 + dt) * 16 + r) * 2 + h5) * 32 + c] = o_acc[dt][r];
        if (h5 == 0) cL[qsel * 32 + c] = half_l;
    }
    __syncthreads();
    if (ksel == 0) {
        const float l = half_l + cL[qsel * 32 + c];
        const float inv = 1.0f / l;
        short* crow = concat + ((size_t)(b * SEQ + qq)) * DMODEL + h * DKH;
        for (int dt = 0; dt < 2; dt++)
            for (int j2 = 0; j2 < 4; j2++) {
                const int r = j2 * 4;
                float o0 = (o_acc[dt][r + 0] + cO[(((qsel * 2 + dt) * 16 + r + 0) * 2 + h5) * 32 + c]) * inv;
                float o1 = (o_acc[dt][r + 1] + cO[(((qsel * 2 + dt) * 16 + r + 1) * 2 + h5) * 32 + c]) * inv;
                float o2 = (o_acc[dt][r + 2] + cO[(((qsel * 2 + dt) * 16 + r + 2) * 2 + h5) * 32 + c]) * inv;
                float o3 = (o_acc[dt][r + 3] + cO[(((qsel * 2 + dt) * 16 + r + 3) * 2 + h5) * 32 + c]) * inv;
                union { unsigned u[2]; s16x4 v; } pk;
                pk.u[0] = cvtpk(o0, o1);
                pk.u[1] = cvtpk(o2, o3);
                const int dk = dt * 32 + 8 * j2 + 4 * h5;
                *(s16x4*)&crow[dk] = pk.v;
            }
    }
}

extern "C" void kernel_launch(void* const* d_in, const int* in_sizes, int n_in,
                              void* d_out, int out_size, void* d_ws, size_t ws_size,
                              hipStream_t stream) {
    const float* q  = (const float*)d_in[0];
    const float* k  = (const float*)d_in[1];
    const float* v  = (const float*)d_in[2];
    const float* Wq = (const float*)d_in[3];
    const float* bq = (const float*)d_in[4];
    const float* Wk = (const float*)d_in[5];
    const float* bk = (const float*)d_in[6];
    const float* Wv = (const float*)d_in[7];
    const float* bv = (const float*)d_in[8];
    const float* Wo = (const float*)d_in[9];
    const float* bo = (const float*)d_in[10];

    const size_t nElemH = (size_t)BATCH * NHEAD * SEQ * DKH;  // 4,194,304
    const size_t nElemW = (size_t)DMODEL * DMODEL;            // 262,144
    short* Qh    = (short*)d_ws;
    short* Kh    = Qh + nElemH;
    short* Vt    = Kh + nElemH;
    short* bfbuf = Vt + nElemH;      // qb|kb|vb|Wqb|Wkb|Wvb|Wob contiguous
    short* qb    = bfbuf;
    short* kb    = qb + nElemH;
    short* vb    = kb + nElemH;
    short* Wqb   = vb + nElemH;
    short* Wkb   = Wqb + nElemW;
    short* Wvb   = Wkb + nElemW;
    short* Wob   = Wvb + nElemW;
    // concat aliases qb: qb is dead once qkv_kernel completes (stream-ordered
    // before attn writes concat). Saves 8 MB of ws.
    short* concat = qb;

    dim3 blk(256);
    convert_kernel<<<dim3(6656), blk, 0, stream>>>(q, k, v, Wq, Wk, Wv, Wo, bfbuf);
    qkv_kernel<<<dim3(MROWS / 128, DMODEL / 128, 3), blk, 0, stream>>>(
        qb, kb, vb, Wqb, Wkb, Wvb, bq, bk, bv, Qh, Kh, Vt);
    attn_kernel<<<dim3(SEQ / 64, BATCH * NHEAD), blk, 0, stream>>>(Qh, Kh, Vt, concat);
    oproj_kernel<<<dim3(MROWS / 128, DMODEL / 128), blk, 0, stream>>>(
        Wob, concat, bo, (float*)d_out);
}

// Round 9
// 235.965 us; speedup vs baseline: 1.0148x; 1.0148x over previous
//
#include <hip/hip_runtime.h>
#include <hip/hip_bf16.h>

#define NHEAD 8
#define DKH 64
#define DMODEL 512
#define SEQ 4096
#define BATCH 2
#define MROWS (BATCH * SEQ)  // 8192

using bf16x8 = __attribute__((ext_vector_type(8))) short;
using s16x4  = __attribute__((ext_vector_type(4))) short;
using f32x4  = __attribute__((ext_vector_type(4))) float;
using f32x16 = __attribute__((ext_vector_type(16))) float;

__device__ __forceinline__ float b2f(unsigned short u) {
    union { unsigned short u; __hip_bfloat16 h; } c; c.u = u; return __bfloat162float(c.h);
}
// round-half-up f32->bf16: 2 VALU ops, max rel err 2^-9.
__device__ __forceinline__ short rhu(float x) {
    union { float f; unsigned u; } c; c.f = x;
    return (short)((c.u + 0x8000u) >> 16);
}

// HW convert+pack: two f32 -> one dword of 2 bf16 (RNE). 1 VALU instr.
__device__ __forceinline__ unsigned cvtpk(float lo, float hi) {
    unsigned r;
    asm("v_cvt_pk_bf16_f32 %0, %1, %2" : "=v"(r) : "v"(lo), "v"(hi));
    return r;
}

// Bare v_exp_f32 (2^x). Fixed-max softmax keeps inputs in normal range.
#if __has_builtin(__builtin_amdgcn_exp2f)
#define EXP2F(x) __builtin_amdgcn_exp2f(x)
#else
#define EXP2F(x) exp2f(x)
#endif

// Direct global->LDS DMA, 16 B/lane. LDS dest must be WAVE-UNIFORM base
// (HW adds lane*16); global src is per-lane (m104/m173).
__device__ __forceinline__ void gload_lds16(const void* g, void* l) {
    __builtin_amdgcn_global_load_lds(
        (const __attribute__((address_space(1))) void*)g,
        (__attribute__((address_space(3))) void*)l,
        16, 0, 0);
}

// ---------------------------------------------------------------------------
// Pre-convert pass: fp32 -> bf16 for q,k,v and all four weight matrices so
// every GEMM operand stages via global_load_lds. Memory-bound (~81 MB moved,
// ~15 us). dst segments contiguous: qb | kb | vb | Wqb | Wkb | Wvb | Wob.
// ---------------------------------------------------------------------------
#define QG ((size_t)MROWS * DMODEL / 8)   // 524288 8-elem groups per tensor
#define WG ((size_t)DMODEL * DMODEL / 8)  // 32768 per weight

__global__ __launch_bounds__(256) void convert_kernel(
    const float* __restrict__ q, const float* __restrict__ k, const float* __restrict__ v,
    const float* __restrict__ Wq, const float* __restrict__ Wk,
    const float* __restrict__ Wv, const float* __restrict__ Wo,
    short* __restrict__ dst) {
    const size_t i = (size_t)blockIdx.x * 256 + threadIdx.x;  // 8-elem group
    const float* src;
    size_t off;
    if (i < 3 * QG) {
        size_t s = i / QG;                 // pow2 shift
        off = (i - s * QG) * 8;
        src = (s == 0) ? q : (s == 1) ? k : v;
    } else {
        size_t j = i - 3 * QG;
        size_t s = j / WG;
        off = (j - s * WG) * 8;
        src = (s == 0) ? Wq : (s == 1) ? Wk : (s == 2) ? Wv : Wo;
    }
    float4 a = *(const float4*)(src + off);
    float4 b = *(const float4*)(src + off + 4);
    union { unsigned u[4]; bf16x8 v8; } t;
    t.u[0] = cvtpk(a.x, a.y);
    t.u[1] = cvtpk(a.z, a.w);
    t.u[2] = cvtpk(b.x, b.y);
    t.u[3] = cvtpk(b.z, b.w);
    *(bf16x8*)&dst[i * 8] = t.v8;
}

// ---------------------------------------------------------------------------
// GEMM core — best-of-ledger consolidation (round 8):
//  * K-loop: SINGLE-buffer DMA (round 3; rest=136.4 best). Dbuf (rounds 4-7)
//    cost ~6 us: 64 KB LDS halves blocks/CU (m132); at K=512 the 2-phase
//    pipeline never repays the lost TLP. 32 KB LDS -> 4 blocks/CU; m114
//    wave-level overlap does the latency hiding.
//  * Epilogues: round-5 wide stores (neutral on dbuf, fewer instructions).
//    EPI 1 [Q,K]: m=CHANNEL, n=token -> r spans dk -> 8-B s16x4 stores
//    EPI 2 [V^T]: m=TOKEN, n=channel -> r spans 4 consecutive kappa slots
//    EPI 0 [O]:   m=OUT-CHANNEL, n=token -> 16-B float4 stores
//  * No xcd_remap (round 7: cost ~9 us; working set is L3-resident, m160).
// ---------------------------------------------------------------------------
template <int EPI, int TM>
__device__ __forceinline__ void gemm_core(const short* __restrict__ A,
                                          const short* __restrict__ W,
                                          const float* __restrict__ bias,
                                          void* __restrict__ out,
                                          int bm, int bn) {
    constexpr int MT = TM / 32;            // 16-row tiles per wave (m dir)
    constexpr int AI = TM / 32;            // lA DMA instrs per wave
    __shared__ __align__(128) short lA[TM * 64];
    __shared__ __align__(128) short lB[128 * 64];

    const int tid  = threadIdx.x;
    const int lane = tid & 63;
    const int w    = tid >> 6;
    const int wr = w >> 1, wc = w & 1;
    const int g = lane >> 4, ln = lane & 15;
    const int l8 = lane >> 3, cb = lane & 7;   // DMA: row-in-group, col-group
    const int sw8 = cb ^ l8;                   // pre-swizzled global k8-group

    const f32x4 zero = {0.f, 0.f, 0.f, 0.f};
    f32x4 acc[MT][4];
    for (int mt = 0; mt < MT; mt++)
        for (int nt = 0; nt < 4; nt++) acc[mt][nt] = zero;

    for (int kb = 0; kb < DMODEL; kb += 64) {
        for (int i = 0; i < AI; i++) {
            const int rb = w * (8 * AI) + i * 8;     // wave-uniform row base
            gload_lds16(&A[(size_t)(bm + rb + l8) * DMODEL + kb + sw8 * 8],
                        &lA[rb * 64]);
        }
        for (int i = 0; i < 4; i++) {
            const int rb = w * 32 + i * 8;
            gload_lds16(&W[(size_t)(bn + rb + l8) * DMODEL + kb + sw8 * 8],
                        &lB[rb * 64]);
        }
        __syncthreads();   // vmcnt(0) drain

        for (int ks = 0; ks < 2; ks++) {
            const int xr = (ks * 4 + g) ^ (ln & 7);  // swizzled 16B slot
            bf16x8 af[MT], bf[4];
            for (int mt = 0; mt < MT; mt++) {
                const int row = wr * 16 * MT + mt * 16 + ln;
                af[mt] = *(const bf16x8*)&lA[row * 64 + xr * 8];
            }
            for (int nt = 0; nt < 4; nt++) {
                const int row = wc * 64 + nt * 16 + ln;
                bf[nt] = *(const bf16x8*)&lB[row * 64 + xr * 8];
            }
            for (int mt = 0; mt < MT; mt++)
                for (int nt = 0; nt < 4; nt++)
                    acc[mt][nt] = __builtin_amdgcn_mfma_f32_16x16x32_bf16(
                        af[mt], bf[nt], acc[mt][nt], 0, 0, 0);
        }
        __syncthreads();
    }

    if (EPI == 1) {
        // m = channel, n = token. 8-B stores.
        for (int mt = 0; mt < MT; mt++) {
            const int ch = bm + wr * 16 * MT + mt * 16 + g * 4;   // quad base
            const int hh = ch >> 6, dk = ch & 63;
            const float4 bz = *(const float4*)&bias[ch];
            for (int nt = 0; nt < 4; nt++) {
                const int n = bn + wc * 64 + nt * 16 + ln;        // token
                const int bb = n >> 12, s = n & 4095;
                union { unsigned u[2]; s16x4 v; } pk;
                pk.u[0] = cvtpk(acc[mt][nt][0] + bz.x, acc[mt][nt][1] + bz.y);
                pk.u[1] = cvtpk(acc[mt][nt][2] + bz.z, acc[mt][nt][3] + bz.w);
                *(s16x4*)&((short*)out)[(((size_t)(bb * NHEAD + hh)) * SEQ + s) * DKH + dk] = pk.v;
            }
        }
    } else if (EPI == 2) {
        // m = token, n = channel. Quad-aligned tokens -> 4 consecutive kappa.
        for (int mt = 0; mt < MT; mt++) {
            const int m = bm + wr * 16 * MT + mt * 16 + g * 4;    // token quad
            const int bb = m >> 12, s = m & 4095;
            const int sl = s & 127, sh = s & ~127;
            const int kt = sl >> 5, kk = sl & 31;                 // lo = 0
            const int t = kk >> 3, hb = (kk >> 2) & 1;
            const int kap = kt * 32 + (t >> 1) * 16 + hb * 8 + (t & 1) * 4;
            for (int nt = 0; nt < 4; nt++) {
                const int chn = bn + wc * 64 + nt * 16 + ln;      // channel
                const int hh = chn >> 6, dk = chn & 63;
                const float bz = bias[chn];
                union { unsigned u[2]; s16x4 v; } pk;
                pk.u[0] = cvtpk(acc[mt][nt][0] + bz, acc[mt][nt][1] + bz);
                pk.u[1] = cvtpk(acc[mt][nt][2] + bz, acc[mt][nt][3] + bz);
                *(s16x4*)&((short*)out)[(((size_t)(bb * NHEAD + hh)) * DKH + dk) * SEQ + sh + kap] = pk.v;
            }
        }
    } else {
        // EPI 0: m = out-channel, n = token. 16-B float4 stores.
        for (int mt = 0; mt < MT; mt++) {
            const int ch = bm + wr * 16 * MT + mt * 16 + g * 4;
            const float4 bz = *(const float4*)&bias[ch];
            for (int nt = 0; nt < 4; nt++) {
                const int n = bn + wc * 64 + nt * 16 + ln;        // token
                float4 o;
                o.x = acc[mt][nt][0] + bz.x;
                o.y = acc[mt][nt][1] + bz.y;
                o.z = acc[mt][nt][2] + bz.z;
                o.w = acc[mt][nt][3] + bz.w;
                *(float4*)&((float*)out)[(size_t)n * DMODEL + ch] = o;
            }
        }
    }
}

// Merged Q/K/V projections (plain tile mapping, no remap).
// z=0 Q, z=1 K: A = weights (channels on M), B = data (tokens on N).
// z=2 V: A = data (tokens on M), B = weights (channels on N).
__global__ __launch_bounds__(256) void qkv_kernel(
    const short* __restrict__ qb, const short* __restrict__ kb, const short* __restrict__ vb,
    const short* __restrict__ Wqb, const short* __restrict__ Wkb, const short* __restrict__ Wvb,
    const float* __restrict__ bq, const float* __restrict__ bk, const float* __restrict__ bv,
    short* __restrict__ Qh, short* __restrict__ Kh, short* __restrict__ Vt) {
    if (blockIdx.z == 0) {
        gemm_core<1, 128>(Wqb, qb, bq, Qh, blockIdx.y * 128, blockIdx.x * 128);
    } else if (blockIdx.z == 1) {
        gemm_core<1, 128>(Wkb, kb, bk, Kh, blockIdx.y * 128, blockIdx.x * 128);
    } else {
        gemm_core<2, 128>(vb, Wvb, bv, Vt, blockIdx.x * 128, blockIdx.y * 128);
    }
}

// oproj: A = Wo (out-channels on M, TM=64), B = concat (tokens on N).
// Grid 64x8 = 512 blocks; 24 KB LDS -> high co-residency.
__global__ __launch_bounds__(256) void oproj_kernel(
    const short* __restrict__ Wob, const short* __restrict__ concat,
    const float* __restrict__ bias, float* __restrict__ out) {
    gemm_core<0, 64>(Wob, concat, bias, out, blockIdx.y * 64, blockIdx.x * 128);
}

// ---------------------------------------------------------------------------
// Flash attention — round-7 verified body: stage -> sync -> compute -> sync
// with T5 setprio around both MFMA clusters (r7: 93.9 -> 88.0 us, MfmaUtil
// 33 -> 36). r6's register-staged T14 pipeline failed correctness and is
// quarantined. History: r0 cvtpk+exp2 diet 140.9 -> 93.3 us.
// ---------------------------------------------------------------------------
__global__ __launch_bounds__(256, 4) void attn_kernel(
    const short* __restrict__ Qh, const short* __restrict__ Kh,
    const short* __restrict__ Vt, short* __restrict__ concat) {
    const int tid  = threadIdx.x;
    const int lane = tid & 63;
    const int w    = tid >> 6;
    const int c  = lane & 31;
    const int h5 = lane >> 5;
    const int qsel = w & 1;
    const int ksel = w >> 1;
    const int bh = blockIdx.y;
    const int b = bh >> 3, h = bh & 7;
    const int qq = blockIdx.x * 64 + qsel * 32 + c;

    const short* Qp = Qh + (size_t)bh * SEQ * DKH;
    const short* Kp = Kh + (size_t)bh * SEQ * DKH;
    const short* Vp = Vt + (size_t)bh * DKH * SEQ;   // [dk][perm(s)]

    __shared__ __align__(16) char smem[35840];
    short* lK = (short*)smem;              // [128][72]
    short* lV = (short*)(smem + 18432);    // [64][136]
    float* cO = (float*)smem;              // combine area (aliased)
    float* cL = (float*)(smem + 32768);

    const float QS = 0.125f * 1.44269504f;
    bf16x8 qf[4];
    for (int ks = 0; ks < 4; ks++) {
        bf16x8 raw = *(const bf16x8*)&Qp[(size_t)qq * DKH + ks * 16 + h5 * 8];
        union { unsigned u[4]; bf16x8 v; } t;
        for (int j = 0; j < 4; j++)
            t.u[j] = cvtpk(b2f((unsigned short)raw[2 * j]) * QS,
                           b2f((unsigned short)raw[2 * j + 1]) * QS);
        qf[ks] = t.v;
    }

    float l_self = 0.f;
    f32x16 o_acc[2];
    for (int dt = 0; dt < 2; dt++)
        for (int r = 0; r < 16; r++) o_acc[dt][r] = 0.f;

    for (int kb = 0; kb < SEQ; kb += 128) {
        for (int i = 0; i < 4; i++) {
            int vv = tid + i * 256;
            {
                int row = vv >> 3, cv = vv & 7;
                *(bf16x8*)&lK[row * 72 + cv * 8] =
                    *(const bf16x8*)&Kp[(size_t)(kb + row) * DKH + cv * 8];
            }
            {
                int dk = vv >> 4, kc = vv & 15;
                *(bf16x8*)&lV[dk * 136 + kc * 8] =
                    *(const bf16x8*)&Vp[(size_t)dk * SEQ + kb + kc * 8];
            }
        }
        __syncthreads();

        f32x16 st[2];
        for (int kt = 0; kt < 2; kt++)
            for (int r = 0; r < 16; r++) st[kt][r] = -12.f;
        __builtin_amdgcn_s_setprio(1);
        for (int ks = 0; ks < 4; ks++)
            for (int kt = 0; kt < 2; kt++) {
                bf16x8 kf = *(const bf16x8*)&lK[(ksel * 64 + kt * 32 + c) * 72 + ks * 16 + h5 * 8];
                st[kt] = __builtin_amdgcn_mfma_f32_32x32x16_bf16(kf, qf[ks], st[kt], 0, 0, 0);
            }
        __builtin_amdgcn_s_setprio(0);

        for (int kt = 0; kt < 2; kt++)
            for (int r = 0; r < 16; r++) {
                float p = EXP2F(st[kt][r]);
                st[kt][r] = p;
                l_self += p;
            }

        __builtin_amdgcn_s_setprio(1);
        for (int ks2 = 0; ks2 < 4; ks2++) {
            const int kt = ks2 >> 1, ob = 8 * (ks2 & 1);
            union { unsigned u[4]; bf16x8 v; } pf;
            for (int j = 0; j < 4; j++)
                pf.u[j] = cvtpk(st[kt][ob + 2 * j], st[kt][ob + 2 * j + 1]);
            const int colg = (ksel * 4 + ks2) * 16 + h5 * 8;
            for (int dt = 0; dt < 2; dt++) {
                bf16x8 vf = *(const bf16x8*)&lV[(dt * 32 + c) * 136 + colg];
                o_acc[dt] = __builtin_amdgcn_mfma_f32_32x32x16_bf16(vf, pf.v, o_acc[dt], 0, 0, 0);
            }
        }
        __builtin_amdgcn_s_setprio(0);
        __syncthreads();
    }

    const float half_l = l_self + __shfl_xor(l_self, 32);
    if (ksel == 1) {
        for (int dt = 0; dt < 2; dt++)
            for (int r = 0; r < 16; r++)
                cO[(((qsel * 2 + dt) * 16 + r) * 2 + h5) * 32 + c] = o_acc[dt][r];
        if (h5 == 0) cL[qsel * 32 + c] = half_l;
    }
    __syncthreads();
    if (ksel == 0) {
        const float l = half_l + cL[qsel * 32 + c];
        const float inv = 1.0f / l;
        short* crow = concat + ((size_t)(b * SEQ + qq)) * DMODEL + h * DKH;
        for (int dt = 0; dt < 2; dt++)
            for (int j2 = 0; j2 < 4; j2++) {
                const int r = j2 * 4;
                float o0 = (o_acc[dt][r + 0] + cO[(((qsel * 2 + dt) * 16 + r + 0) * 2 + h5) * 32 + c]) * inv;
                float o1 = (o_acc[dt][r + 1] + cO[(((qsel * 2 + dt) * 16 + r + 1) * 2 + h5) * 32 + c]) * inv;
                float o2 = (o_acc[dt][r + 2] + cO[(((qsel * 2 + dt) * 16 + r + 2) * 2 + h5) * 32 + c]) * inv;
                float o3 = (o_acc[dt][r + 3] + cO[(((qsel * 2 + dt) * 16 + r + 3) * 2 + h5) * 32 + c]) * inv;
                union { unsigned u[2]; s16x4 v; } pk;
                pk.u[0] = cvtpk(o0, o1);
                pk.u[1] = cvtpk(o2, o3);
                const int dk = dt * 32 + 8 * j2 + 4 * h5;
                *(s16x4*)&crow[dk] = pk.v;
            }
    }
}

extern "C" void kernel_launch(void* const* d_in, const int* in_sizes, int n_in,
                              void* d_out, int out_size, void* d_ws, size_t ws_size,
                              hipStream_t stream) {
    const float* q  = (const float*)d_in[0];
    const float* k  = (const float*)d_in[1];
    const float* v  = (const float*)d_in[2];
    const float* Wq = (const float*)d_in[3];
    const float* bq = (const float*)d_in[4];
    const float* Wk = (const float*)d_in[5];
    const float* bk = (const float*)d_in[6];
    const float* Wv = (const float*)d_in[7];
    const float* bv = (const float*)d_in[8];
    const float* Wo = (const float*)d_in[9];
    const float* bo = (const float*)d_in[10];

    const size_t nElemH = (size_t)BATCH * NHEAD * SEQ * DKH;  // 4,194,304
    const size_t nElemW = (size_t)DMODEL * DMODEL;            // 262,144
    short* Qh    = (short*)d_ws;
    short* Kh    = Qh + nElemH;
    short* Vt    = Kh + nElemH;
    short* bfbuf = Vt + nElemH;      // qb|kb|vb|Wqb|Wkb|Wvb|Wob contiguous
    short* qb    = bfbuf;
    short* kb    = qb + nElemH;
    short* vb    = kb + nElemH;
    short* Wqb   = vb + nElemH;
    short* Wkb   = Wqb + nElemW;
    short* Wvb   = Wkb + nElemW;
    short* Wob   = Wvb + nElemW;
    // concat aliases qb: qb is dead once qkv_kernel completes (stream-ordered
    // before attn writes concat). Saves 8 MB of ws.
    short* concat = qb;

    dim3 blk(256);
    convert_kernel<<<dim3(6656), blk, 0, stream>>>(q, k, v, Wq, Wk, Wv, Wo, bfbuf);
    qkv_kernel<<<dim3(MROWS / 128, DMODEL / 128, 3), blk, 0, stream>>>(
        qb, kb, vb, Wqb, Wkb, Wvb, bq, bk, bv, Qh, Kh, Vt);
    attn_kernel<<<dim3(SEQ / 64, BATCH * NHEAD), blk, 0, stream>>>(Qh, Kh, Vt, concat);
    oproj_kernel<<<dim3(MROWS / 128, DMODEL / 64), blk, 0, stream>>>(
        Wob, concat, bo, (float*)d_out);
}

// Round 10
// 226.465 us; speedup vs baseline: 1.0574x; 1.0419x over previous
//
#include <hip/hip_runtime.h>
#include <hip/hip_bf16.h>

#define NHEAD 8
#define DKH 64
#define DMODEL 512
#define SEQ 4096
#define BATCH 2
#define MROWS (BATCH * SEQ)  // 8192

using bf16x8 = __attribute__((ext_vector_type(8))) short;
using s16x4  = __attribute__((ext_vector_type(4))) short;
using f32x4  = __attribute__((ext_vector_type(4))) float;
using f32x16 = __attribute__((ext_vector_type(16))) float;

__device__ __forceinline__ float b2f(unsigned short u) {
    union { unsigned short u; __hip_bfloat16 h; } c; c.u = u; return __bfloat162float(c.h);
}
// round-half-up f32->bf16: 2 VALU ops, max rel err 2^-9.
__device__ __forceinline__ short rhu(float x) {
    union { float f; unsigned u; } c; c.f = x;
    return (short)((c.u + 0x8000u) >> 16);
}

// HW convert+pack: two f32 -> one dword of 2 bf16 (RNE). 1 VALU instr.
__device__ __forceinline__ unsigned cvtpk(float lo, float hi) {
    unsigned r;
    asm("v_cvt_pk_bf16_f32 %0, %1, %2" : "=v"(r) : "v"(lo), "v"(hi));
    return r;
}

// Bare v_exp_f32 (2^x). Fixed-max softmax keeps inputs in normal range.
#if __has_builtin(__builtin_amdgcn_exp2f)
#define EXP2F(x) __builtin_amdgcn_exp2f(x)
#else
#define EXP2F(x) exp2f(x)
#endif

// Direct global->LDS DMA, 16 B/lane. LDS dest must be WAVE-UNIFORM base
// (HW adds lane*16); global src is per-lane (m104/m173).
__device__ __forceinline__ void gload_lds16(const void* g, void* l) {
    __builtin_amdgcn_global_load_lds(
        (const __attribute__((address_space(1))) void*)g,
        (__attribute__((address_space(3))) void*)l,
        16, 0, 0);
}

// ---------------------------------------------------------------------------
// Pre-convert pass: fp32 -> bf16 for q,k,v and all four weight matrices so
// every GEMM operand stages via global_load_lds. Memory-bound (~81 MB moved,
// ~13 us = at BW ceiling). dst: qb | kb | vb | Wqb | Wkb | Wvb | Wob.
// ---------------------------------------------------------------------------
#define QG ((size_t)MROWS * DMODEL / 8)   // 524288 8-elem groups per tensor
#define WG ((size_t)DMODEL * DMODEL / 8)  // 32768 per weight

__global__ __launch_bounds__(256) void convert_kernel(
    const float* __restrict__ q, const float* __restrict__ k, const float* __restrict__ v,
    const float* __restrict__ Wq, const float* __restrict__ Wk,
    const float* __restrict__ Wv, const float* __restrict__ Wo,
    short* __restrict__ dst) {
    const size_t i = (size_t)blockIdx.x * 256 + threadIdx.x;  // 8-elem group
    const float* src;
    size_t off;
    if (i < 3 * QG) {
        size_t s = i / QG;                 // pow2 shift
        off = (i - s * QG) * 8;
        src = (s == 0) ? q : (s == 1) ? k : v;
    } else {
        size_t j = i - 3 * QG;
        size_t s = j / WG;
        off = (j - s * WG) * 8;
        src = (s == 0) ? Wq : (s == 1) ? Wk : (s == 2) ? Wv : Wo;
    }
    float4 a = *(const float4*)(src + off);
    float4 b = *(const float4*)(src + off + 4);
    union { unsigned u[4]; bf16x8 v8; } t;
    t.u[0] = cvtpk(a.x, a.y);
    t.u[1] = cvtpk(a.z, a.w);
    t.u[2] = cvtpk(b.x, b.y);
    t.u[3] = cvtpk(b.z, b.w);
    *(bf16x8*)&dst[i * 8] = t.v8;
}

// ---------------------------------------------------------------------------
// GEMM core — EXACT round-3 structure (best measured rest = 136.4 us, R4
// bench): single-buffer width-16 global_load_lds into linear LDS [row][64],
// XOR-swizzled both-sides (rule #21); 2-barrier K-loop (m114 wave-level TLP
// does the pipelining; dbuf cost ~6 us via occupancy, m132); SCALAR
// epilogues with channel-per-lane orientation (contiguous 32-B runs across
// lanes; round 9's token-major wide stores cost ~12 us: 8 B/lane at 128-B
// stride = 64 lines touched per store instr).
// EPI 0: out[m*512+n] fp32                            [oproj]
// EPI 1: head scatter [b,h,s,dk], bf16                [Q,K proj]
// EPI 2: permuted V^T scatter [b,h,dk,perm(s)], bf16  [V proj]
// ---------------------------------------------------------------------------
template <int EPI, int TM>
__device__ __forceinline__ void gemm_core(const short* __restrict__ A,
                                          const short* __restrict__ W,
                                          const float* __restrict__ bias,
                                          void* __restrict__ out,
                                          int bm, int bn) {
    constexpr int MT = TM / 32;            // 16-row tiles per wave (m dir)
    constexpr int AI = TM / 32;            // lA DMA instrs per wave
    __shared__ __align__(128) short lA[TM * 64];
    __shared__ __align__(128) short lB[128 * 64];

    const int tid  = threadIdx.x;
    const int lane = tid & 63;
    const int w    = tid >> 6;
    const int wr = w >> 1, wc = w & 1;
    const int g = lane >> 4, ln = lane & 15;
    const int l8 = lane >> 3, cb = lane & 7;   // DMA: row-in-group, col-group
    const int sw8 = cb ^ l8;                   // pre-swizzled global k8-group

    const f32x4 zero = {0.f, 0.f, 0.f, 0.f};
    f32x4 acc[MT][4];
    for (int mt = 0; mt < MT; mt++)
        for (int nt = 0; nt < 4; nt++) acc[mt][nt] = zero;

    for (int kb = 0; kb < DMODEL; kb += 64) {
        for (int i = 0; i < AI; i++) {
            const int rb = w * (8 * AI) + i * 8;     // wave-uniform row base
            gload_lds16(&A[(size_t)(bm + rb + l8) * DMODEL + kb + sw8 * 8],
                        &lA[rb * 64]);
        }
        for (int i = 0; i < 4; i++) {
            const int rb = w * 32 + i * 8;
            gload_lds16(&W[(size_t)(bn + rb + l8) * DMODEL + kb + sw8 * 8],
                        &lB[rb * 64]);
        }
        __syncthreads();   // compiler emits vmcnt(0) drain here

        for (int ks = 0; ks < 2; ks++) {
            const int xr = (ks * 4 + g) ^ (ln & 7);  // swizzled 16B slot
            bf16x8 af[MT], bf[4];
            for (int mt = 0; mt < MT; mt++) {
                const int row = wr * 16 * MT + mt * 16 + ln;
                af[mt] = *(const bf16x8*)&lA[row * 64 + xr * 8];
            }
            for (int nt = 0; nt < 4; nt++) {
                const int row = wc * 64 + nt * 16 + ln;
                bf[nt] = *(const bf16x8*)&lB[row * 64 + xr * 8];
            }
            for (int mt = 0; mt < MT; mt++)
                for (int nt = 0; nt < 4; nt++)
                    acc[mt][nt] = __builtin_amdgcn_mfma_f32_16x16x32_bf16(
                        af[mt], bf[nt], acc[mt][nt], 0, 0, 0);
        }
        __syncthreads();
    }

    if (EPI == 2) {
        for (int mt = 0; mt < MT; mt++) {
            for (int r = 0; r < 4; r++) {
                const int m = bm + wr * 16 * MT + mt * 16 + g * 4 + r;  // channel
                const float bz = ((const float*)bias)[m];
                const int hh = m >> 6, dk = m & 63;
                for (int nt = 0; nt < 4; nt++) {
                    const int n = bn + wc * 64 + nt * 16 + ln;          // token
                    const int bb = n >> 12, s = n & 4095;
                    const int sl = s & 127, sh = s & ~127;
                    const int kt = sl >> 5, kk = sl & 31;
                    const int t = kk >> 3, hb = (kk >> 2) & 1, lo = kk & 3;
                    const int kappa = kt * 32 + (t >> 1) * 16 + hb * 8 + (t & 1) * 4 + lo;
                    ((short*)out)[(((size_t)(bb * NHEAD + hh)) * DKH + dk) * SEQ + sh + kappa] =
                        rhu(acc[mt][nt][r] + bz);
                }
            }
        }
    } else {
        for (int nt = 0; nt < 4; nt++) {
            const int n = bn + wc * 64 + nt * 16 + ln;
            const float bz = ((const float*)bias)[n];
            for (int mt = 0; mt < MT; mt++) {
                for (int r = 0; r < 4; r++) {
                    const int m = bm + wr * 16 * MT + mt * 16 + g * 4 + r;
                    const float val = acc[mt][nt][r] + bz;
                    if (EPI == 1) {
                        const int bb = m >> 12, s = m & 4095;
                        const int hh = n >> 6, dk = n & 63;
                        ((short*)out)[(((size_t)(bb * NHEAD + hh)) * SEQ + s) * DKH + dk] =
                            rhu(val);
                    } else {
                        ((float*)out)[(size_t)m * DMODEL + n] = val;
                    }
                }
            }
        }
    }
}

// Merged Q/K/V projections: z=0 Q, z=1 K (EPI1, A=data tokens on M);
// z=2 V^T (EPI2, A=weights channels on M, coords swapped).
__global__ __launch_bounds__(256) void qkv_kernel(
    const short* __restrict__ qb, const short* __restrict__ kb, const short* __restrict__ vb,
    const short* __restrict__ Wqb, const short* __restrict__ Wkb, const short* __restrict__ Wvb,
    const float* __restrict__ bq, const float* __restrict__ bk, const float* __restrict__ bv,
    short* __restrict__ Qh, short* __restrict__ Kh, short* __restrict__ Vt) {
    if (blockIdx.z == 0) {
        gemm_core<1, 128>(qb, Wqb, bq, Qh, blockIdx.x * 128, blockIdx.y * 128);
    } else if (blockIdx.z == 1) {
        gemm_core<1, 128>(kb, Wkb, bk, Kh, blockIdx.x * 128, blockIdx.y * 128);
    } else {
        // vproj operand-swapped: rows = channels (y), cols = tokens (x)
        gemm_core<2, 128>(Wvb, vb, bv, Vt, blockIdx.y * 128, blockIdx.x * 128);
    }
}

// oproj: A = concat (tokens on M, TM=64), W = Wo. 512 blocks, 24 KB LDS.
__global__ __launch_bounds__(256) void oproj_kernel(
    const short* __restrict__ A, const short* __restrict__ W,
    const float* __restrict__ bias, float* __restrict__ out) {
    gemm_core<0, 64>(A, W, bias, out, blockIdx.x * 64, blockIdx.y * 128);
}

// ---------------------------------------------------------------------------
// Flash attention — round-7 verified body (88.0/87.8 us twice): stage ->
// sync -> compute -> sync with T5 setprio around both MFMA clusters
// (r7: 93.9 -> 88.0, MfmaUtil 33 -> 36). r0 cvtpk+exp2 diet: 140.9 -> 93.3.
// r6's register-staged T14 pipeline failed correctness; quarantined.
// ---------------------------------------------------------------------------
__global__ __launch_bounds__(256, 4) void attn_kernel(
    const short* __restrict__ Qh, const short* __restrict__ Kh,
    const short* __restrict__ Vt, short* __restrict__ concat) {
    const int tid  = threadIdx.x;
    const int lane = tid & 63;
    const int w    = tid >> 6;
    const int c  = lane & 31;
    const int h5 = lane >> 5;
    const int qsel = w & 1;
    const int ksel = w >> 1;
    const int bh = blockIdx.y;
    const int b = bh >> 3, h = bh & 7;
    const int qq = blockIdx.x * 64 + qsel * 32 + c;

    const short* Qp = Qh + (size_t)bh * SEQ * DKH;
    const short* Kp = Kh + (size_t)bh * SEQ * DKH;
    const short* Vp = Vt + (size_t)bh * DKH * SEQ;   // [dk][perm(s)]

    __shared__ __align__(16) char smem[35840];
    short* lK = (short*)smem;              // [128][72]
    short* lV = (short*)(smem + 18432);    // [64][136]
    float* cO = (float*)smem;              // combine area (aliased)
    float* cL = (float*)(smem + 32768);

    const float QS = 0.125f * 1.44269504f;
    bf16x8 qf[4];
    for (int ks = 0; ks < 4; ks++) {
        bf16x8 raw = *(const bf16x8*)&Qp[(size_t)qq * DKH + ks * 16 + h5 * 8];
        union { unsigned u[4]; bf16x8 v; } t;
        for (int j = 0; j < 4; j++)
            t.u[j] = cvtpk(b2f((unsigned short)raw[2 * j]) * QS,
                           b2f((unsigned short)raw[2 * j + 1]) * QS);
        qf[ks] = t.v;
    }

    float l_self = 0.f;
    f32x16 o_acc[2];
    for (int dt = 0; dt < 2; dt++)
        for (int r = 0; r < 16; r++) o_acc[dt][r] = 0.f;

    for (int kb = 0; kb < SEQ; kb += 128) {
        for (int i = 0; i < 4; i++) {
            int vv = tid + i * 256;
            {
                int row = vv >> 3, cv = vv & 7;
                *(bf16x8*)&lK[row * 72 + cv * 8] =
                    *(const bf16x8*)&Kp[(size_t)(kb + row) * DKH + cv * 8];
            }
            {
                int dk = vv >> 4, kc = vv & 15;
                *(bf16x8*)&lV[dk * 136 + kc * 8] =
                    *(const bf16x8*)&Vp[(size_t)dk * SEQ + kb + kc * 8];
            }
        }
        __syncthreads();

        f32x16 st[2];
        for (int kt = 0; kt < 2; kt++)
            for (int r = 0; r < 16; r++) st[kt][r] = -12.f;
        __builtin_amdgcn_s_setprio(1);
        for (int ks = 0; ks < 4; ks++)
            for (int kt = 0; kt < 2; kt++) {
                bf16x8 kf = *(const bf16x8*)&lK[(ksel * 64 + kt * 32 + c) * 72 + ks * 16 + h5 * 8];
                st[kt] = __builtin_amdgcn_mfma_f32_32x32x16_bf16(kf, qf[ks], st[kt], 0, 0, 0);
            }
        __builtin_amdgcn_s_setprio(0);

        for (int kt = 0; kt < 2; kt++)
            for (int r = 0; r < 16; r++) {
                float p = EXP2F(st[kt][r]);
                st[kt][r] = p;
                l_self += p;
            }

        __builtin_amdgcn_s_setprio(1);
        for (int ks2 = 0; ks2 < 4; ks2++) {
            const int kt = ks2 >> 1, ob = 8 * (ks2 & 1);
            union { unsigned u[4]; bf16x8 v; } pf;
            for (int j = 0; j < 4; j++)
                pf.u[j] = cvtpk(st[kt][ob + 2 * j], st[kt][ob + 2 * j + 1]);
            const int colg = (ksel * 4 + ks2) * 16 + h5 * 8;
            for (int dt = 0; dt < 2; dt++) {
                bf16x8 vf = *(const bf16x8*)&lV[(dt * 32 + c) * 136 + colg];
                o_acc[dt] = __builtin_amdgcn_mfma_f32_32x32x16_bf16(vf, pf.v, o_acc[dt], 0, 0, 0);
            }
        }
        __builtin_amdgcn_s_setprio(0);
        __syncthreads();
    }

    const float half_l = l_self + __shfl_xor(l_self, 32);
    if (ksel == 1) {
        for (int dt = 0; dt < 2; dt++)
            for (int r = 0; r < 16; r++)
                cO[(((qsel * 2 + dt) * 16 + r) * 2 + h5) * 32 + c] = o_acc[dt][r];
        if (h5 == 0) cL[qsel * 32 + c] = half_l;
    }
    __syncthreads();
    if (ksel == 0) {
        const float l = half_l + cL[qsel * 32 + c];
        const float inv = 1.0f / l;
        short* crow = concat + ((size_t)(b * SEQ + qq)) * DMODEL + h * DKH;
        for (int dt = 0; dt < 2; dt++)
            for (int j2 = 0; j2 < 4; j2++) {
                const int r = j2 * 4;
                float o0 = (o_acc[dt][r + 0] + cO[(((qsel * 2 + dt) * 16 + r + 0) * 2 + h5) * 32 + c]) * inv;
                float o1 = (o_acc[dt][r + 1] + cO[(((qsel * 2 + dt) * 16 + r + 1) * 2 + h5) * 32 + c]) * inv;
                float o2 = (o_acc[dt][r + 2] + cO[(((qsel * 2 + dt) * 16 + r + 2) * 2 + h5) * 32 + c]) * inv;
                float o3 = (o_acc[dt][r + 3] + cO[(((qsel * 2 + dt) * 16 + r + 3) * 2 + h5) * 32 + c]) * inv;
                union { unsigned u[2]; s16x4 v; } pk;
                pk.u[0] = cvtpk(o0, o1);
                pk.u[1] = cvtpk(o2, o3);
                const int dk = dt * 32 + 8 * j2 + 4 * h5;
                *(s16x4*)&crow[dk] = pk.v;
            }
    }
}

extern "C" void kernel_launch(void* const* d_in, const int* in_sizes, int n_in,
                              void* d_out, int out_size, void* d_ws, size_t ws_size,
                              hipStream_t stream) {
    const float* q  = (const float*)d_in[0];
    const float* k  = (const float*)d_in[1];
    const float* v  = (const float*)d_in[2];
    const float* Wq = (const float*)d_in[3];
    const float* bq = (const float*)d_in[4];
    const float* Wk = (const float*)d_in[5];
    const float* bk = (const float*)d_in[6];
    const float* Wv = (const float*)d_in[7];
    const float* bv = (const float*)d_in[8];
    const float* Wo = (const float*)d_in[9];
    const float* bo = (const float*)d_in[10];

    const size_t nElemH = (size_t)BATCH * NHEAD * SEQ * DKH;  // 4,194,304
    const size_t nElemW = (size_t)DMODEL * DMODEL;            // 262,144
    short* Qh    = (short*)d_ws;
    short* Kh    = Qh + nElemH;
    short* Vt    = Kh + nElemH;
    short* bfbuf = Vt + nElemH;      // qb|kb|vb|Wqb|Wkb|Wvb|Wob contiguous
    short* qb    = bfbuf;
    short* kb    = qb + nElemH;
    short* vb    = kb + nElemH;
    short* Wqb   = vb + nElemH;
    short* Wkb   = Wqb + nElemW;
    short* Wvb   = Wkb + nElemW;
    short* Wob   = Wvb + nElemW;
    // concat aliases qb: qb is dead once qkv_kernel completes (stream-ordered
    // before attn writes concat). Saves 8 MB of ws.
    short* concat = qb;

    dim3 blk(256);
    convert_kernel<<<dim3(6656), blk, 0, stream>>>(q, k, v, Wq, Wk, Wv, Wo, bfbuf);
    qkv_kernel<<<dim3(MROWS / 128, DMODEL / 128, 3), blk, 0, stream>>>(
        qb, kb, vb, Wqb, Wkb, Wvb, bq, bk, bv, Qh, Kh, Vt);
    attn_kernel<<<dim3(SEQ / 64, BATCH * NHEAD), blk, 0, stream>>>(Qh, Kh, Vt, concat);
    oproj_kernel<<<dim3(MROWS / 64, DMODEL / 128), blk, 0, stream>>>(
        concat, Wob, bo, (float*)d_out);
}